// Round 7
// baseline (490.211 us; speedup 1.0000x reference)
//
#include <hip/hip_runtime.h>

// Problem constants
#define BATCH 4096
#define INF   2048
#define OUTF  2048

typedef __attribute__((ext_vector_type(8))) short bf16x8;
typedef __attribute__((ext_vector_type(4))) float f32x4;

// float -> bf16 bits, round-to-nearest-even
__device__ inline unsigned short f2bf(float f) {
  unsigned int u = __float_as_uint(f);
  u += 0x7fffu + ((u >> 16) & 1u);
  return (unsigned short)(u >> 16);
}

// 16B async global->LDS. LDS dest is wave-uniform base; HW writes base + lane*16.
__device__ inline void gld16(const void* g, void* l) {
  __builtin_amdgcn_global_load_lds(
      (const __attribute__((address_space(1))) void*)g,
      (__attribute__((address_space(3))) void*)l,
      16, 0, 0);
}

// Fused pack: x_re,x_im (4096x2048) and w_re,w_im (2048x2048) fp32 -> bf16,
// plain row-major (no concatenation, no duplication).
__global__ __launch_bounds__(256) void pack_all(const float* __restrict__ xr,
                                                const float* __restrict__ xi,
                                                const float* __restrict__ wr,
                                                const float* __restrict__ wi,
                                                unsigned short* __restrict__ Xre,
                                                unsigned short* __restrict__ Xim,
                                                unsigned short* __restrict__ Wr,
                                                unsigned short* __restrict__ Wi) {
  const int XCH = (BATCH * INF) / 8;   // 1048576 ushort8 chunks for each x matrix
  int t = blockIdx.x * 256 + threadIdx.x;
  const float4 *s0, *s1;
  bf16x8 *d0, *d1;
  int idx;
  if (t < XCH) {
    idx = t;
    s0 = (const float4*)xr; s1 = (const float4*)xi;
    d0 = (bf16x8*)Xre;      d1 = (bf16x8*)Xim;
  } else {
    idx = t - XCH;                      // < (OUTF*INF)/8 = 524288
    s0 = (const float4*)wr; s1 = (const float4*)wi;
    d0 = (bf16x8*)Wr;       d1 = (bf16x8*)Wi;
  }
  float4 a0 = s0[2 * idx], a1 = s0[2 * idx + 1];
  float4 b0 = s1[2 * idx], b1 = s1[2 * idx + 1];
  bf16x8 v0, v1;
  v0[0] = (short)f2bf(a0.x); v0[1] = (short)f2bf(a0.y);
  v0[2] = (short)f2bf(a0.z); v0[3] = (short)f2bf(a0.w);
  v0[4] = (short)f2bf(a1.x); v0[5] = (short)f2bf(a1.y);
  v0[6] = (short)f2bf(a1.z); v0[7] = (short)f2bf(a1.w);
  v1[0] = (short)f2bf(b0.x); v1[1] = (short)f2bf(b0.y);
  v1[2] = (short)f2bf(b0.z); v1[3] = (short)f2bf(b0.w);
  v1[4] = (short)f2bf(b1.x); v1[5] = (short)f2bf(b1.y);
  v1[6] = (short)f2bf(b1.z); v1[7] = (short)f2bf(b1.w);
  d0[idx] = v0;
  d1[idx] = v1;
}

// Fused complex GEMM over K=2048.
// out[b,o,0] = Xre.Wr^T - Xim.Wi^T ; out[b,o,1] = Xre.Wi^T + Xim.Wr^T
// 128x128 block tile, 4 waves (2x2), each 64x64 via 4x4 mfma 16x16x32 bf16.
//
// Round-7 structure (from the R6 pipe model: wall = MFMA pipe 159K cy + LDS
// pipe 135K cy, perfectly serialized):
//  * X fragments NEVER touch LDS: loaded global->VGPR one FULL K-step (64)
//    ahead into a double register set (~9000 cy latency cover; R3 failed with
//    only ~600 cy cover). With the R6 XCD patch remap the X slice is
//    L2-resident, so these are L2-hits.
//  * W double-buffered in LDS (2 x 32 KB halves of sWr/sWi = 64 KB total,
//    still 2 blocks/CU). Stage for kt+64 issues at the TOP of step kt.
//  * Sync per K-step: counted `s_waitcnt vmcnt(24)` (drains exactly the
//    previous step's 8 W-gld16 + 16 X-loads, keeps this step's 24 in flight)
//    + ONE raw s_barrier. No vmcnt(0) drain anywhere in the loop; barrier
//    count halved vs R0.
//    Buffer safety: step kt reads buf[p], writes buf[p^1]; buf[p] is
//    re-written at step kt+128, which every wave reaches only after passing
//    the kt+64 barrier, which it reaches only after its kt reads completed
//    (MFMA consumed them). One barrier/step suffices.
// LDS chunk swizzle for W identical to R0.
__global__ __launch_bounds__(256, 2) void cgemm(const unsigned short* __restrict__ Xre,
                                                const unsigned short* __restrict__ Xim,
                                                const unsigned short* __restrict__ Wr,
                                                const unsigned short* __restrict__ Wi,
                                                float* __restrict__ out) {
  __shared__ unsigned short sWr[2 * 8192];  // 2 bufs x 16 KB
  __shared__ unsigned short sWi[2 * 8192];

  const int tid  = threadIdx.x;
  const int wid  = tid >> 6;
  const int lane = tid & 63;
  const int lrow = lane & 15;
  const int lhi  = lane >> 4;
  const int wm   = wid >> 1;
  const int wn   = wid & 1;

  // R6 XCD patch remap: xcd = wg&7 owns an 8bm x 8bn patch (patches 4x2).
  const int wg  = blockIdx.y * 16 + blockIdx.x;   // grid (16,32)
  const int xcd = wg & 7;
  const int o   = wg >> 3;
  const int bm0 = (((xcd >> 1) << 3) + (o >> 3)) * 128;   // batch tile
  const int bn0 = (((xcd & 1) << 3) + (o & 7)) * 128;     // out-feature tile

  // W staging map (R0 scheme): LDS(r,c) holds global chunk c^s(r),
  // s(r)=(r&3)^((r>>2)&3).
  const int srow = tid >> 2;                        // 0..63 (+64 for 2nd gld)
  const int sc   = tid & 3;
  const int ss   = (srow & 3) ^ ((srow >> 2) & 3);  // same for srow and srow+64
  const int scol = (sc ^ ss) * 8;                   // shorts within 32-wide half

  const unsigned short* gWr = Wr + (size_t)(bn0 + srow) * INF + scol;
  const unsigned short* gWi = Wi + (size_t)(bn0 + srow) * INF + scol;
  const int ldsoff = wid * 1024;   // bytes within a buffer

  // W fragment read swizzle: logical k-chunk lhi -> LDS chunk lhi^s(row).
  const int slane  = (lrow & 3) ^ ((lrow >> 2) & 3);
  const int kchunk = (lhi ^ slane) * 8;             // shorts

  // X direct per-lane base (MFMA A-frag layout: lane(lrow,lhi), row lrow,
  // k-chunk lhi*8; rows i*16 apart).
  const unsigned short* pXre = Xre + (size_t)(bm0 + wm * 64 + lrow) * INF + lhi * 8;
  const unsigned short* pXim = Xim + (size_t)(bm0 + wm * 64 + lrow) * INF + lhi * 8;

  f32x4 accre[4][4], accim[4][4];
  const f32x4 zz = {0.f, 0.f, 0.f, 0.f};
#pragma unroll
  for (int i = 0; i < 4; ++i)
#pragma unroll
    for (int j = 0; j < 4; ++j) { accre[i][j] = zz; accim[i][j] = zz; }

  const bf16x8 SGN = {(short)0x8000, (short)0x8000, (short)0x8000, (short)0x8000,
                      (short)0x8000, (short)0x8000, (short)0x8000, (short)0x8000};

  // 8 gld16: W (r,i) for K-step kt into buffer at byte offset WB (0 / 16384).
#define STAGE_W(KT, WB)                                                   \
  {                                                                       \
    _Pragma("unroll")                                                     \
    for (int h = 0; h < 2; ++h) {                                         \
      const int go = (KT) + h * 32;                                       \
      const int lo = (WB) + h * 8192 + ldsoff;                            \
      gld16(gWr + go,                    (char*)sWr + lo);                \
      gld16(gWr + go + (size_t)64 * INF, (char*)sWr + lo + 4096);         \
      gld16(gWi + go,                    (char*)sWi + lo);                \
      gld16(gWi + go + (size_t)64 * INF, (char*)sWi + lo + 4096);         \
    }                                                                     \
  }

  // 16 global 16B loads: X fragments for K-step KT into reg set (XR, XI).
#define LOADX(XR, XI, KT)                                                 \
  {                                                                       \
    _Pragma("unroll")                                                     \
    for (int i = 0; i < 4; ++i) {                                         \
      _Pragma("unroll")                                                   \
      for (int h = 0; h < 2; ++h) {                                       \
        XR[i][h] = *(const bf16x8*)&pXre[(size_t)(i * 16) * INF + (KT) + h * 32]; \
        XI[i][h] = *(const bf16x8*)&pXim[(size_t)(i * 16) * INF + (KT) + h * 32]; \
      }                                                                   \
    }                                                                     \
  }

  // One K-step: optionally issue next step's stage+prefetch, counted wait,
  // one barrier, then 2 x (8 ds_read + 64 MFMA) consuming reg set (XCR,XCI).
#define BODY(XCR, XCI, XNR, XNI, RB, WB, KT, PRE, WAITIMM)                \
  {                                                                       \
    if (PRE) {                                                            \
      STAGE_W((KT) + 64, WB);                                             \
      LOADX(XNR, XNI, (KT) + 64);                                         \
    }                                                                     \
    __builtin_amdgcn_sched_barrier(0);                                    \
    asm volatile("s_waitcnt vmcnt(" WAITIMM ")" ::: "memory");            \
    __builtin_amdgcn_s_barrier();                                         \
    _Pragma("unroll")                                                     \
    for (int h = 0; h < 2; ++h) {                                         \
      const int hb = (RB) + h * 4096;  /* shorts */                       \
      bf16x8 wr_[4], wi_[4], wn_[4];                                      \
      _Pragma("unroll")                                                   \
      for (int j = 0; j < 4; ++j) {                                       \
        wr_[j] = *(const bf16x8*)&sWr[hb + (wn * 64 + j * 16 + lrow) * 32 + kchunk]; \
        wi_[j] = *(const bf16x8*)&sWi[hb + (wn * 64 + j * 16 + lrow) * 32 + kchunk]; \
        wn_[j] = wi_[j] ^ SGN;                                            \
      }                                                                   \
      _Pragma("unroll")                                                   \
      for (int i = 0; i < 4; ++i) {                                       \
        _Pragma("unroll")                                                 \
        for (int j = 0; j < 4; ++j) {                                     \
          accre[i][j] = __builtin_amdgcn_mfma_f32_16x16x32_bf16(XCR[i][h], wr_[j], accre[i][j], 0, 0, 0); \
          accre[i][j] = __builtin_amdgcn_mfma_f32_16x16x32_bf16(XCI[i][h], wn_[j], accre[i][j], 0, 0, 0); \
          accim[i][j] = __builtin_amdgcn_mfma_f32_16x16x32_bf16(XCR[i][h], wi_[j], accim[i][j], 0, 0, 0); \
          accim[i][j] = __builtin_amdgcn_mfma_f32_16x16x32_bf16(XCI[i][h], wr_[j], accim[i][j], 0, 0, 0); \
        }                                                                 \
      }                                                                   \
    }                                                                     \
  }

  bf16x8 xAr[4][2], xAi[4][2], xBr[4][2], xBi[4][2];

  // Prologue: stage W[0] -> buf0, prefetch X[0] -> set A. (24 in flight.)
  STAGE_W(0, 0)
  LOADX(xAr, xAi, 0)

  // Steady state: 30 steps in pairs; each body issues 24 (8 W + 16 X) for
  // kt+64, then vmcnt(24) drains exactly the 24 issued one step earlier.
  int kt = 0;
#pragma unroll 1
  for (int it = 0; it < 15; ++it) {
    BODY(xAr, xAi, xBr, xBi, 0,    16384, kt,      1, "24")
    BODY(xBr, xBi, xAr, xAi, 8192, 0,     kt + 64, 1, "24")
    kt += 128;
  }
  // kt == 1920: stage/prefetch 1984, then final step drains everything.
  BODY(xAr, xAi, xBr, xBi, 0,    16384, 1920, 1, "24")
  BODY(xBr, xBi, xAr, xAi, 8192, 0,     1984, 0, "0")

#undef BODY
#undef LOADX
#undef STAGE_W

  // Epilogue: C/D layout col=lane&15, row=(lane>>4)*4+reg. Interleaved {re,im}.
  const int row0 = bm0 + wm * 64 + lhi * 4;
  const int col0 = bn0 + wn * 64 + lrow;
#pragma unroll
  for (int i = 0; i < 4; ++i)
#pragma unroll
    for (int j = 0; j < 4; ++j)
#pragma unroll
      for (int r = 0; r < 4; ++r) {
        int row = row0 + i * 16 + r;
        int col = col0 + j * 16;
        float2 v = make_float2(accre[i][j][r], accim[i][j][r]);
        *(float2*)&out[((size_t)row * OUTF + col) * 2] = v;
      }
}

// Safety fallback if workspace too small: fp32 vector path (slow but correct)
__global__ __launch_bounds__(256) void naive_cx(const float* __restrict__ xr,
                                                const float* __restrict__ xi,
                                                const float* __restrict__ wr,
                                                const float* __restrict__ wi,
                                                float* __restrict__ out) {
  int t = blockIdx.x * 256 + threadIdx.x;
  int b = t >> 11, o = t & 2047;
  const float* xrb = xr + (size_t)b * INF;
  const float* xib = xi + (size_t)b * INF;
  const float* wrb = wr + (size_t)o * INF;
  const float* wib = wi + (size_t)o * INF;
  float are = 0.f, aim = 0.f;
  for (int i = 0; i < INF; ++i) {
    float a = xrb[i], c = xib[i], p = wrb[i], q = wib[i];
    are += a * p - c * q;
    aim += a * q + c * p;
  }
  out[(size_t)t * 2 + 0] = are;
  out[(size_t)t * 2 + 1] = aim;
}

extern "C" void kernel_launch(void* const* d_in, const int* in_sizes, int n_in,
                              void* d_out, int out_size, void* d_ws, size_t ws_size,
                              hipStream_t stream) {
  const float* xr = (const float*)d_in[0];
  const float* xi = (const float*)d_in[1];
  const float* wr = (const float*)d_in[2];
  const float* wi = (const float*)d_in[3];
  float* out = (float*)d_out;

  const size_t nx = (size_t)BATCH * INF;   // 8M elements per x matrix
  const size_t nw = (size_t)OUTF * INF;    // 4M elements per w matrix
  const size_t need = (2 * nx + 2 * nw) * sizeof(unsigned short);  // 48 MiB

  if (ws_size < need) {
    naive_cx<<<(BATCH * OUTF) / 256, 256, 0, stream>>>(xr, xi, wr, wi, out);
    return;
  }

  unsigned short* Xre = (unsigned short*)d_ws;
  unsigned short* Xim = Xre + nx;
  unsigned short* Wr  = Xim + nx;
  unsigned short* Wi  = Wr + nw;

  // pack_all: one thread per ushort8 chunk of each (re,im) pair
  const int grid_pack = (int)((nx / 8 + nw / 8) / 256);           // 6144
  pack_all<<<grid_pack, 256, 0, stream>>>(xr, xi, wr, wi, Xre, Xim, Wr, Wi);

  dim3 grid(OUTF / 128, BATCH / 128);   // 16 x 32 = 512 blocks
  cgemm<<<grid, 256, 0, stream>>>(Xre, Xim, Wr, Wi, out);
}